// Round 4
// baseline (752.918 us; speedup 1.0000x reference)
//
#include <hip/hip_runtime.h>
#include <math.h>

typedef unsigned short u16;
typedef unsigned int u32;
typedef __attribute__((ext_vector_type(8))) short bf16x8;   // 8 bf16 (4 VGPRs)
typedef __attribute__((ext_vector_type(4))) float f32x4;    // 4 fp32 acc

#define NN 50000    // nodes
#define NE 800000   // edges
#define F0 1433     // in feats
#define KP 1440     // padded K (45 * 32)
#define MP 50048    // padded M (391 * 128)
#define D1 256
#define D2 32
#define NB 196      // scan blocks: 196*256 = 50176 >= NN
#define HB 3125     // hist blocks: 3125*256 >= NE
#define PGB 12512   // pad blocks: one per 4-row group; 12500 real + 12 zero (-> MP rows)
#define SB 3125     // scatter blocks

__device__ __forceinline__ float bf2f(u16 h) { return __uint_as_float(((u32)h) << 16); }
__device__ __forceinline__ u16 f2bf(float f) {
  u32 u = __float_as_uint(f);
  u32 r = (u + 0x7FFFu + ((u >> 16) & 1u)) >> 16;  // RNE
  return (u16)r;
}

// async global->LDS, 16B per lane; LDS dest is wave-uniform base + lane*16
__device__ __forceinline__ void gl16(const void* g, void* l) {
  __builtin_amdgcn_global_load_lds((const __attribute__((address_space(1))) u32*)g,
                                   (__attribute__((address_space(3))) u32*)l, 16, 0, 0);
}

// ---------------- merged: edge histogram (blocks 0..HB) + pad/convert features ----------------
// pad part: one block per 4-row group. 4 rows = 22928 B = 16*1433 -> float4-aligned, contiguous.
// Register-only: 6 predicated unrolled float4 loads (all in flight), convert in regs,
// 4 posted global_store_shorts per float4. No LDS, no barrier.
// Out byte offset of element ee (0..5731) within group: 2*ee + 14*(ee/F0).
__global__ __launch_bounds__(256) void k_histpad(const int* __restrict__ ei,
                                                 int* __restrict__ cs, int* __restrict__ cd,
                                                 const float* __restrict__ F, u16* __restrict__ P) {
  if (blockIdx.x < HB) {
    const int e = blockIdx.x * 256 + threadIdx.x;
    if (e < NE) {
      atomicAdd(&cs[ei[e]], 1);
      atomicAdd(&cd[ei[NE + e]], 1);
    }
    return;
  }
  const int g = blockIdx.x - HB;       // 4-row group id, 0..PGB-1
  const int t = threadIdx.x;
  u16* gout = P + (size_t)g * 4 * KP;  // 11520 B per group, 16B aligned

  if (g >= NN / 4) {                   // zero groups (rows 50000..50047)
    uint4* go4 = (uint4*)gout;
    const uint4 z = {0u, 0u, 0u, 0u};
    for (int idx = t; idx < 720; idx += 256) go4[idx] = z;
    return;
  }

  // zero the 7-col pad tail of each of the 4 rows (28 shorts)
  if (t < 28) gout[(t / 7) * KP + F0 + (t % 7)] = (u16)0;

  const float4* src4 = (const float4*)(F + (size_t)g * 4 * F0);  // 16B aligned: 4*F0*4 = 22928 = 16*1433
  float4 v[6];
  bool ok[6];
#pragma unroll
  for (int j = 0; j < 6; ++j) {        // all loads issued before any use
    const int idx = t + j * 256;
    ok[j] = (idx < F0);
    if (ok[j]) v[j] = src4[idx];
  }
#pragma unroll
  for (int j = 0; j < 6; ++j) {
    if (ok[j]) {
      const int e0 = (t + j * 256) * 4;
      const float fv[4] = {v[j].x, v[j].y, v[j].z, v[j].w};
#pragma unroll
      for (int jj = 0; jj < 4; ++jj) {
        const int ee = e0 + jj;        // 0..5731
        const int r = ee / F0;         // magic-mul
        const int c = ee - r * F0;
        gout[r * KP + c] = f2bf(fv[jj]);
      }
    }
  }
}

__global__ __launch_bounds__(256) void k_scan1(const int* __restrict__ cd, int* __restrict__ bsum) {
  __shared__ int sh[256];
  const int t = threadIdx.x;
  const int i = blockIdx.x * 256 + t;
  sh[t] = (i < NN) ? cd[i] : 0;
  __syncthreads();
  for (int o = 128; o > 0; o >>= 1) {
    if (t < o) sh[t] += sh[t + o];
    __syncthreads();
  }
  if (t == 0) bsum[blockIdx.x] = sh[0];
}

__global__ __launch_bounds__(256) void k_scan2(const int* __restrict__ bsum, int* __restrict__ boff) {
  __shared__ int sh[256];
  const int t = threadIdx.x;
  const int v = (t < NB) ? bsum[t] : 0;
  sh[t] = v;
  __syncthreads();
  for (int o = 1; o < 256; o <<= 1) {
    int x = (t >= o) ? sh[t - o] : 0;
    __syncthreads();
    sh[t] += x;
    __syncthreads();
  }
  if (t < NB) boff[t] = sh[t] - v;  // exclusive
}

// exclusive scan per block + base; emits row_start, cursor, and both norms
__global__ __launch_bounds__(256) void k_scan3(const int* __restrict__ cd, const int* __restrict__ cs,
                                               const int* __restrict__ boff,
                                               int* __restrict__ row, int* __restrict__ cur,
                                               float* __restrict__ cdst, float* __restrict__ csrc) {
  __shared__ int sh[256];
  const int t = threadIdx.x;
  const int i = blockIdx.x * 256 + t;
  const int v = (i < NN) ? cd[i] : 0;
  sh[t] = v;
  __syncthreads();
  for (int o = 1; o < 256; o <<= 1) {
    int x = (t >= o) ? sh[t - o] : 0;
    __syncthreads();
    sh[t] += x;
    __syncthreads();
  }
  if (i < NN) {
    const int start = boff[blockIdx.x] + sh[t] - v;
    row[i] = start;
    cur[i] = start;
    if (i == NN - 1) row[NN] = start + v;
    cdst[i] = rsqrtf(fmaxf((float)v, 1.0f));
    csrc[i] = rsqrtf(fmaxf((float)cs[i], 1.0f));
  }
}

// ---------------- merged: CSR scatter (blocks 0..SB) + weight prep (blocks SB..) ----------------
// W1 fp32[F0][256] -> bf16 W1T[256][KP]; W2 fp32[256][32] -> bf16 W2T[32][256]
__global__ __launch_bounds__(256) void k_scatprep(const int* __restrict__ ei,
                                                  int* __restrict__ cur, int* __restrict__ csr,
                                                  const float* __restrict__ W1, const float* __restrict__ W2,
                                                  u16* __restrict__ W1T, u16* __restrict__ W2T) {
  const int bid = blockIdx.x;
  const int t = threadIdx.x;
  if (bid < SB) {
    const int e = bid * 256 + t;
    if (e < NE) {
      const int d = ei[NE + e];
      const int p = atomicAdd(&cur[d], 1);
      csr[p] = ei[e];
    }
    return;
  }
  const int b = bid - SB;
  if (b < KP) {
    W1T[(size_t)t * KP + b] = (b < F0) ? f2bf(W1[(size_t)b * D1 + t]) : (u16)0;
  } else {
    const int idx = (b - KP) * 256 + t;  // 0..8191
    const int k = idx & 255, n = idx >> 8;
    W2T[n * 256 + k] = f2bf(W2[k * 32 + n]);
  }
}

// ---------------- GEMM1: padA[MP][KP] @ W1T[256][KP]^T -> h1 bf16 [NN][256], epilogue * c_src ----------------
// 1-D grid 782, bijective XCD-chunked swizzle so the tn-pair sharing an A-tile lands on one XCD's L2.
__global__ __launch_bounds__(256) void k_gemm1(const u16* __restrict__ A, const u16* __restrict__ BT,
                                               const float* __restrict__ csrc, u16* __restrict__ H) {
  __shared__ u16 As[128 * 32];
  __shared__ u16 Bs[128 * 32];
  const int tid = threadIdx.x;
  const int wave = tid >> 6, lane = tid & 63;
  const int l16 = lane & 15, quad = lane >> 4;
  const int waveM = wave & 1, waveN = wave >> 1;

  // nwg = 782 = 8*97 + 6: chunks of 98 (xcd<6) / 97 (xcd>=6). blk wg runs on XCD wg%8.
  const int wg = blockIdx.x;
  const int xcd = wg & 7, idx = wg >> 3;
  const int swz = (xcd < 6) ? xcd * 98 + idx : 588 + (xcd - 6) * 97 + idx;
  const int tn = swz & 1, tm = swz >> 1;

  f32x4 acc[4][4];
#pragma unroll
  for (int mi = 0; mi < 4; ++mi)
#pragma unroll
    for (int ni = 0; ni < 4; ++ni) acc[mi][ni] = f32x4{0.f, 0.f, 0.f, 0.f};

  // staging: 512 16B chunks per tile; chunk c -> LDS byte 16*c; row c>>2, k-quad c&3
  const int c0 = wave * 64 + lane;
  const int rA0 = c0 >> 2, qA0 = (c0 & 3) * 8;
  const u16* Ab = A + (size_t)tm * 128 * KP;
  const u16* Bb = BT + (size_t)tn * 128 * KP;
  u16* As0 = As + (wave * 64) * 8;           // wave-uniform LDS bases
  u16* As1 = As + (wave * 64 + 256) * 8;
  u16* Bs0 = Bs + (wave * 64) * 8;
  u16* Bs1 = Bs + (wave * 64 + 256) * 8;
  const size_t off0 = (size_t)rA0 * KP + qA0;
  const size_t off1 = (size_t)(rA0 + 64) * KP + qA0;

  for (int kt = 0; kt < KP / 32; ++kt) {
    const int k0 = kt * 32;
    __syncthreads();
    gl16(Ab + off0 + k0, As0);
    gl16(Ab + off1 + k0, As1);
    gl16(Bb + off0 + k0, Bs0);
    gl16(Bb + off1 + k0, Bs1);
    __syncthreads();
    bf16x8 af[4], bfr[4];
#pragma unroll
    for (int mi = 0; mi < 4; ++mi)
      af[mi] = *(const bf16x8*)(As + ((waveM * 64 + mi * 16 + l16) * 32 + quad * 8));
#pragma unroll
    for (int ni = 0; ni < 4; ++ni)
      bfr[ni] = *(const bf16x8*)(Bs + ((waveN * 64 + ni * 16 + l16) * 32 + quad * 8));
#pragma unroll
    for (int mi = 0; mi < 4; ++mi)
#pragma unroll
      for (int ni = 0; ni < 4; ++ni)
        acc[mi][ni] = __builtin_amdgcn_mfma_f32_16x16x32_bf16(af[mi], bfr[ni], acc[mi][ni], 0, 0, 0);
  }

  // C/D: col = lane&15, row = quad*4 + reg  (verified m89/m91)
  const int rbase = tm * 128 + waveM * 64 + quad * 4;
  const int cbase = tn * 128 + waveN * 64 + l16;
#pragma unroll
  for (int mi = 0; mi < 4; ++mi) {
#pragma unroll
    for (int e = 0; e < 4; ++e) {
      const int i = rbase + mi * 16 + e;
      if (i < NN) {
        const float cs = csrc[i];
#pragma unroll
        for (int ni = 0; ni < 4; ++ni)
          H[(size_t)i * D1 + cbase + ni * 16] = f2bf(acc[mi][ni][e] * cs);
      }
    }
  }
}

// ---------------- fused SpMM1+post1: x1s[d] = relu(sum_{s in N(d)} h1[s] * cdst[d] + b1) * csrc[d] ----------------
// unroll 4: four gathers in flight behind the index loads
__global__ __launch_bounds__(256) void k_spmm1f(const int* __restrict__ row, const int* __restrict__ csr,
                                                const u16* __restrict__ h1, const float* __restrict__ cdst,
                                                const float* __restrict__ csrc, const float* __restrict__ b1,
                                                u16* __restrict__ x) {
  const int d = blockIdx.x * 4 + (threadIdx.x >> 6);   // grid exact: 12500*4 = NN
  const int lane = threadIdx.x & 63;
  const int rs = row[d], re = row[d + 1];
  float a0 = 0.f, a1 = 0.f, a2 = 0.f, a3 = 0.f;
  int e = rs;
  for (; e + 3 < re; e += 4) {
    const int s0 = csr[e], s1 = csr[e + 1], s2 = csr[e + 2], s3 = csr[e + 3];
    const ushort4 v0 = *(const ushort4*)(h1 + (size_t)s0 * D1 + lane * 4);
    const ushort4 v1 = *(const ushort4*)(h1 + (size_t)s1 * D1 + lane * 4);
    const ushort4 v2 = *(const ushort4*)(h1 + (size_t)s2 * D1 + lane * 4);
    const ushort4 v3 = *(const ushort4*)(h1 + (size_t)s3 * D1 + lane * 4);
    a0 += (bf2f(v0.x) + bf2f(v1.x)) + (bf2f(v2.x) + bf2f(v3.x));
    a1 += (bf2f(v0.y) + bf2f(v1.y)) + (bf2f(v2.y) + bf2f(v3.y));
    a2 += (bf2f(v0.z) + bf2f(v1.z)) + (bf2f(v2.z) + bf2f(v3.z));
    a3 += (bf2f(v0.w) + bf2f(v1.w)) + (bf2f(v2.w) + bf2f(v3.w));
  }
  for (; e < re; ++e) {
    const int s0 = csr[e];
    const ushort4 v0 = *(const ushort4*)(h1 + (size_t)s0 * D1 + lane * 4);
    a0 += bf2f(v0.x); a1 += bf2f(v0.y); a2 += bf2f(v0.z); a3 += bf2f(v0.w);
  }
  const float cd = cdst[d], cs = csrc[d];
  const float4 bb = *(const float4*)(b1 + lane * 4);
  const float r0 = fmaxf(a0 * cd + bb.x, 0.f) * cs;
  const float r1 = fmaxf(a1 * cd + bb.y, 0.f) * cs;
  const float r2 = fmaxf(a2 * cd + bb.z, 0.f) * cs;
  const float r3 = fmaxf(a3 * cd + bb.w, 0.f) * cs;
  ushort4 o;
  o.x = f2bf(r0); o.y = f2bf(r1); o.z = f2bf(r2); o.w = f2bf(r3);
  *(ushort4*)(x + (size_t)d * D1 + lane * 4) = o;
}

// ---------------- GEMM2: x1s[*][256] @ W2T[32][256]^T -> h2 bf16 [NN][32] ----------------
__global__ __launch_bounds__(256) void k_gemm2(const u16* __restrict__ A, const u16* __restrict__ BT,
                                               u16* __restrict__ H) {
  __shared__ u16 As[128 * 32];
  __shared__ u16 Bs[32 * 32];
  const int tid = threadIdx.x;
  const int wave = tid >> 6, lane = tid & 63;
  const int l16 = lane & 15, quad = lane >> 4;
  const int tm = blockIdx.x;

  f32x4 acc[2][2];
#pragma unroll
  for (int mi = 0; mi < 2; ++mi)
#pragma unroll
    for (int ni = 0; ni < 2; ++ni) acc[mi][ni] = f32x4{0.f, 0.f, 0.f, 0.f};

  const int r0 = tid >> 2, q0 = (tid & 3) * 8;
  int rowA0 = tm * 128 + r0;      if (rowA0 >= NN) rowA0 = NN - 1;
  int rowA1 = tm * 128 + r0 + 64; if (rowA1 >= NN) rowA1 = NN - 1;
  for (int kt = 0; kt < 8; ++kt) {
    const int k0 = kt * 32;
    __syncthreads();
    uint4 v0 = *(const uint4*)(A + (size_t)rowA0 * D1 + k0 + q0);
    uint4 v1 = *(const uint4*)(A + (size_t)rowA1 * D1 + k0 + q0);
    *(uint4*)(As + r0 * 32 + q0) = v0;
    *(uint4*)(As + (r0 + 64) * 32 + q0) = v1;
    if (tid < 128) {
      uint4 vb = *(const uint4*)(BT + (size_t)r0 * D1 + k0 + q0);
      *(uint4*)(Bs + r0 * 32 + q0) = vb;
    }
    __syncthreads();
    bf16x8 af[2], bfr[2];
#pragma unroll
    for (int mi = 0; mi < 2; ++mi)
      af[mi] = *(const bf16x8*)(As + ((wave * 32 + mi * 16 + l16) * 32 + quad * 8));
#pragma unroll
    for (int ni = 0; ni < 2; ++ni)
      bfr[ni] = *(const bf16x8*)(Bs + ((ni * 16 + l16) * 32 + quad * 8));
#pragma unroll
    for (int mi = 0; mi < 2; ++mi)
#pragma unroll
      for (int ni = 0; ni < 2; ++ni)
        acc[mi][ni] = __builtin_amdgcn_mfma_f32_16x16x32_bf16(af[mi], bfr[ni], acc[mi][ni], 0, 0, 0);
  }

  const int rbase = tm * 128 + wave * 32 + quad * 4;
#pragma unroll
  for (int mi = 0; mi < 2; ++mi)
#pragma unroll
    for (int e = 0; e < 4; ++e) {
      const int i = rbase + mi * 16 + e;
      if (i < NN) {
#pragma unroll
        for (int ni = 0; ni < 2; ++ni)
          H[(size_t)i * D2 + ni * 16 + l16] = f2bf(acc[mi][ni][e]);
      }
    }
}

// ---------------- fused SpMM2+post2 ----------------
__global__ __launch_bounds__(256) void k_spmm2f(const int* __restrict__ row, const int* __restrict__ csr,
                                                const u16* __restrict__ h2, const float* __restrict__ cdst,
                                                const float* __restrict__ csrc, const float* __restrict__ b2,
                                                u16* __restrict__ x) {
  const int t = threadIdx.x;
  const int d = blockIdx.x * 8 + (t >> 5);  // grid exact: 6250*8 = NN
  const int f = t & 31;
  const int rs = row[d], re = row[d + 1];
  float acc = 0.f;
  int e = rs;
  for (; e + 3 < re; e += 4) {
    const int s0 = csr[e], s1 = csr[e + 1], s2 = csr[e + 2], s3 = csr[e + 3];
    acc += (bf2f(h2[(size_t)s0 * D2 + f]) + bf2f(h2[(size_t)s1 * D2 + f])) +
           (bf2f(h2[(size_t)s2 * D2 + f]) + bf2f(h2[(size_t)s3 * D2 + f]));
  }
  for (; e < re; ++e) acc += bf2f(h2[(size_t)csr[e] * D2 + f]);
  const float v = acc * cdst[d] + b2[f];
  x[(size_t)d * D2 + f] = f2bf(fmaxf(v, 0.f) * csrc[d]);
}

// ---------------- layer3 matmul: h3[i][c] = sum_k x2s[i][k]*W3[k][c], f32 [NN][8] ----------------
__global__ __launch_bounds__(256) void k_l3(const u16* __restrict__ x, const float* __restrict__ W3,
                                            float* __restrict__ h3) {
  __shared__ float w3s[224];
  const int t = threadIdx.x;
  if (t < 224) w3s[t] = W3[t];
  __syncthreads();
  const int i = blockIdx.x * 256 + t;
  if (i >= NN) return;
  const uint4* p = (const uint4*)(x + (size_t)i * D2);
  union { uint4 v[4]; u16 s[32]; } u;
  u.v[0] = p[0]; u.v[1] = p[1]; u.v[2] = p[2]; u.v[3] = p[3];
  float acc[7];
#pragma unroll
  for (int c = 0; c < 7; ++c) acc[c] = 0.f;
#pragma unroll
  for (int k = 0; k < 32; ++k) {
    const float xv = bf2f(u.s[k]);
#pragma unroll
    for (int c = 0; c < 7; ++c) acc[c] += xv * w3s[k * 7 + c];
  }
  float* o = h3 + (size_t)i * 8;
#pragma unroll
  for (int c = 0; c < 7; ++c) o[c] = acc[c];
}

// ---------------- fused SpMM3 + bias + log_softmax: 8 lanes per node ----------------
__global__ __launch_bounds__(256) void k_spmm3f(const int* __restrict__ row, const int* __restrict__ csr,
                                                const float* __restrict__ h3, const float* __restrict__ cdst,
                                                const float* __restrict__ b3, float* __restrict__ out) {
  const int t = threadIdx.x;
  const int d = blockIdx.x * 32 + (t >> 3);
  const int c = t & 7;
  if (d >= NN) return;
  const int rs = row[d], re = row[d + 1];
  float acc = 0.f;
  if (c < 7) {
    int e = rs;
    for (; e + 1 < re; e += 2)
      acc += h3[(size_t)csr[e] * 8 + c] + h3[(size_t)csr[e + 1] * 8 + c];
    if (e < re) acc += h3[(size_t)csr[e] * 8 + c];
  }
  const float v = (c < 7) ? (acc * cdst[d] + b3[c]) : -INFINITY;
  float m = v;
  m = fmaxf(m, __shfl_xor(m, 1));
  m = fmaxf(m, __shfl_xor(m, 2));
  m = fmaxf(m, __shfl_xor(m, 4));
  float s = (c < 7) ? expf(v - m) : 0.f;
  s += __shfl_xor(s, 1);
  s += __shfl_xor(s, 2);
  s += __shfl_xor(s, 4);
  const float l = logf(s);
  if (c < 7) out[(size_t)d * 7 + c] = v - m - l;
}

// ---------------- workspace layout (bytes) ----------------
static const size_t O_CSRC = 0;           // f32 [NN]
static const size_t O_CDST = 200192;      // f32 [NN]
static const size_t O_ROW  = 400384;      // int [NN+1]
static const size_t O_CUR  = 601088;      // int [NN]
static const size_t O_CNTS = 801792;      // int [NN]
static const size_t O_CNTD = 1002496;     // int [NN]
static const size_t O_BSUM = 1203200;     // int [256]
static const size_t O_BOFF = 1204224;     // int [256]
static const size_t O_CSR  = 1205248;     // int [NE]
static const size_t O_W1T  = 4405248;     // bf16 [256][KP]
static const size_t O_W2T  = 5142528;     // bf16 [32][256]
static const size_t O_H1   = 5158912;     // bf16 [NN][256]
static const size_t O_PADA = 30758912;    // bf16 [MP][KP] = 144.1 MB (dead after gemm1)
static const size_t O_X1S  = O_PADA;                // bf16 [NN][256] (aliases padA)
static const size_t O_H2   = O_PADA + 25600000;     // bf16 [NN][32]
static const size_t O_X2S  = O_PADA + 28800000;     // bf16 [NN][32]
static const size_t O_H3   = O_PADA + 32000000;     // f32 [NN][8]

extern "C" void kernel_launch(void* const* d_in, const int* in_sizes, int n_in,
                              void* d_out, int out_size, void* d_ws, size_t ws_size,
                              hipStream_t stream) {
  const float* feat = (const float*)d_in[0];
  const int* ei     = (const int*)d_in[1];
  const float* W1   = (const float*)d_in[2];
  const float* b1   = (const float*)d_in[3];
  const float* W2   = (const float*)d_in[4];
  const float* b2   = (const float*)d_in[5];
  const float* W3   = (const float*)d_in[6];
  const float* b3   = (const float*)d_in[7];
  float* out = (float*)d_out;

  char* ws = (char*)d_ws;
  float* c_src = (float*)(ws + O_CSRC);
  float* c_dst = (float*)(ws + O_CDST);
  int* row  = (int*)(ws + O_ROW);
  int* cur  = (int*)(ws + O_CUR);
  int* cnts = (int*)(ws + O_CNTS);
  int* cntd = (int*)(ws + O_CNTD);
  int* bsum = (int*)(ws + O_BSUM);
  int* boff = (int*)(ws + O_BOFF);
  int* csr  = (int*)(ws + O_CSR);
  u16* W1T  = (u16*)(ws + O_W1T);
  u16* W2T  = (u16*)(ws + O_W2T);
  u16* h1   = (u16*)(ws + O_H1);
  u16* padA = (u16*)(ws + O_PADA);
  u16* x1s  = (u16*)(ws + O_X1S);
  u16* h2   = (u16*)(ws + O_H2);
  u16* x2s  = (u16*)(ws + O_X2S);
  float* h3 = (float*)(ws + O_H3);

  // CSR histogram runs concurrently with the pad/convert pass (one dispatch)
  hipMemsetAsync(cnts, 0, (size_t)NN * 4, stream);
  hipMemsetAsync(cntd, 0, (size_t)NN * 4, stream);
  k_histpad<<<HB + PGB, 256, 0, stream>>>(ei, cnts, cntd, feat, padA);
  k_scan1<<<NB, 256, 0, stream>>>(cntd, bsum);
  k_scan2<<<1, 256, 0, stream>>>(bsum, boff);
  k_scan3<<<NB, 256, 0, stream>>>(cntd, cnts, boff, row, cur, c_dst, c_src);
  // scatter runs concurrently with weight prep (one dispatch)
  k_scatprep<<<SB + KP + 32, 256, 0, stream>>>(ei, cur, csr, W1, W2, W1T, W2T);

  // layer 1
  k_gemm1<<<782, 256, 0, stream>>>(padA, W1T, c_src, h1);
  k_spmm1f<<<NN / 4, 256, 0, stream>>>(row, csr, h1, c_dst, c_src, b1, x1s);

  // layer 2
  k_gemm2<<<MP / 128, 256, 0, stream>>>(x1s, W2T, h2);
  k_spmm2f<<<NN / 8, 256, 0, stream>>>(row, csr, h2, c_dst, c_src, b2, x2s);

  // layer 3 + log_softmax
  k_l3<<<(NN + 255) / 256, 256, 0, stream>>>(x2s, W3, h3);
  k_spmm3f<<<(NN + 31) / 32, 256, 0, stream>>>(row, csr, h3, c_dst, b3, out);
}

// Round 5
// 710.265 us; speedup vs baseline: 1.0601x; 1.0601x over previous
//
#include <hip/hip_runtime.h>
#include <math.h>

typedef unsigned short u16;
typedef unsigned int u32;
typedef __attribute__((ext_vector_type(8))) short bf16x8;   // 8 bf16 (4 VGPRs)
typedef __attribute__((ext_vector_type(4))) float f32x4;    // 4 fp32 acc
typedef float f32x4u __attribute__((vector_size(16), aligned(4)));  // unaligned-capable float4

#define NN 50000    // nodes
#define NE 800000   // edges
#define F0 1433     // in feats
#define KP 1440     // padded K (45 * 32)
#define MP 50048    // padded M (391 * 128)
#define D1 256
#define D2 32
#define NB 196      // scan blocks: 196*256 = 50176 >= NN
#define HB 3125     // hist blocks: 3125*256 >= NE
#define SB 3125     // scatter blocks

__device__ __forceinline__ float bf2f(u16 h) { return __uint_as_float(((u32)h) << 16); }
__device__ __forceinline__ u16 f2bf(float f) {
  u32 u = __float_as_uint(f);
  u32 r = (u + 0x7FFFu + ((u >> 16) & 1u)) >> 16;  // RNE
  return (u16)r;
}
// packed f32 pair -> bf16 pair (RNE), single HW instr
__device__ __forceinline__ u32 cvtpk(float lo, float hi) {
  u32 r;
  asm("v_cvt_pk_bf16_f32 %0, %1, %2" : "=v"(r) : "v"(lo), "v"(hi));
  return r;
}

// async global->LDS, 16B per lane; LDS dest is wave-uniform base + lane*16
__device__ __forceinline__ void gl16(const void* g, void* l) {
  __builtin_amdgcn_global_load_lds((const __attribute__((address_space(1))) u32*)g,
                                   (__attribute__((address_space(3))) u32*)l, 16, 0, 0);
}

// ---------------- edge histogram (pad pass deleted: gemm1 converts f32 in staging) ----------------
__global__ __launch_bounds__(256) void k_hist(const int* __restrict__ ei,
                                              int* __restrict__ cs, int* __restrict__ cd) {
  const int e = blockIdx.x * 256 + threadIdx.x;
  if (e < NE) {
    atomicAdd(&cs[ei[e]], 1);
    atomicAdd(&cd[ei[NE + e]], 1);
  }
}

__global__ __launch_bounds__(256) void k_scan1(const int* __restrict__ cd, int* __restrict__ bsum) {
  __shared__ int sh[256];
  const int t = threadIdx.x;
  const int i = blockIdx.x * 256 + t;
  sh[t] = (i < NN) ? cd[i] : 0;
  __syncthreads();
  for (int o = 128; o > 0; o >>= 1) {
    if (t < o) sh[t] += sh[t + o];
    __syncthreads();
  }
  if (t == 0) bsum[blockIdx.x] = sh[0];
}

__global__ __launch_bounds__(256) void k_scan2(const int* __restrict__ bsum, int* __restrict__ boff) {
  __shared__ int sh[256];
  const int t = threadIdx.x;
  const int v = (t < NB) ? bsum[t] : 0;
  sh[t] = v;
  __syncthreads();
  for (int o = 1; o < 256; o <<= 1) {
    int x = (t >= o) ? sh[t - o] : 0;
    __syncthreads();
    sh[t] += x;
    __syncthreads();
  }
  if (t < NB) boff[t] = sh[t] - v;  // exclusive
}

// exclusive scan per block + base; emits row_start, cursor, and both norms
__global__ __launch_bounds__(256) void k_scan3(const int* __restrict__ cd, const int* __restrict__ cs,
                                               const int* __restrict__ boff,
                                               int* __restrict__ row, int* __restrict__ cur,
                                               float* __restrict__ cdst, float* __restrict__ csrc) {
  __shared__ int sh[256];
  const int t = threadIdx.x;
  const int i = blockIdx.x * 256 + t;
  const int v = (i < NN) ? cd[i] : 0;
  sh[t] = v;
  __syncthreads();
  for (int o = 1; o < 256; o <<= 1) {
    int x = (t >= o) ? sh[t - o] : 0;
    __syncthreads();
    sh[t] += x;
    __syncthreads();
  }
  if (i < NN) {
    const int start = boff[blockIdx.x] + sh[t] - v;
    row[i] = start;
    cur[i] = start;
    if (i == NN - 1) row[NN] = start + v;
    cdst[i] = rsqrtf(fmaxf((float)v, 1.0f));
    csrc[i] = rsqrtf(fmaxf((float)cs[i], 1.0f));
  }
}

// ---------------- merged: CSR scatter (blocks 0..SB) + weight prep (blocks SB..) ----------------
// W1 fp32[F0][256] -> bf16 W1T[256][KP] (zero pad cols -> A garbage in k>=F0 contributes 0); W2 -> W2T[32][256]
__global__ __launch_bounds__(256) void k_scatprep(const int* __restrict__ ei,
                                                  int* __restrict__ cur, int* __restrict__ csr,
                                                  const float* __restrict__ W1, const float* __restrict__ W2,
                                                  u16* __restrict__ W1T, u16* __restrict__ W2T) {
  const int bid = blockIdx.x;
  const int t = threadIdx.x;
  if (bid < SB) {
    const int e = bid * 256 + t;
    if (e < NE) {
      const int d = ei[NE + e];
      const int p = atomicAdd(&cur[d], 1);
      csr[p] = ei[e];
    }
    return;
  }
  const int b = bid - SB;
  if (b < KP) {
    W1T[(size_t)t * KP + b] = (b < F0) ? f2bf(W1[(size_t)b * D1 + t]) : (u16)0;
  } else {
    const int idx = (b - KP) * 256 + t;  // 0..8191
    const int k = idx & 255, n = idx >> 8;
    W2T[n * 256 + k] = f2bf(W2[k * 32 + n]);
  }
}

// ---------------- GEMM1: F f32[NN][1433] (@ staged-cvt bf16) @ W1T[256][KP]^T -> h1 bf16 [NN][256], * c_src ----------------
// A staging: per K-step each thread loads 2x(8 consecutive f32, align-4), cvt_pk -> bf16x8, ds_write_b128.
// Prefetch for kt+1 issued at top of MFMA phase. B stays global_load_lds. LDS layout/fragments unchanged.
__global__ __launch_bounds__(256) void k_gemm1(const float* __restrict__ F,
                                               const u16* __restrict__ BT,
                                               const float* __restrict__ csrc, u16* __restrict__ H) {
  __shared__ u16 As[128 * 32];
  __shared__ u16 Bs[128 * 32];
  const int tid = threadIdx.x;
  const int wave = tid >> 6, lane = tid & 63;
  const int l16 = lane & 15, quad = lane >> 4;
  const int waveM = wave & 1, waveN = wave >> 1;

  // nwg = 782 = 8*97 + 6: bijective XCD-chunked swizzle; tn-pair sharing an A-panel lands on one XCD's L2.
  const int wg = blockIdx.x;
  const int xcd = wg & 7, idx = wg >> 3;
  const int swz = (xcd < 6) ? xcd * 98 + idx : 588 + (xcd - 6) * 97 + idx;
  const int tn = swz & 1, tm = swz >> 1;

  f32x4 acc[4][4];
#pragma unroll
  for (int mi = 0; mi < 4; ++mi)
#pragma unroll
    for (int ni = 0; ni < 4; ++ni) acc[mi][ni] = f32x4{0.f, 0.f, 0.f, 0.f};

  // staging geometry: 512 16B chunks per tile; chunk c -> LDS byte 16*c; row c>>2, k-quad c&3
  const int c0 = wave * 64 + lane;
  const int rA0 = c0 >> 2, qA0 = (c0 & 3) * 8;
  int ga0 = tm * 128 + rA0;        if (ga0 >= NN) ga0 = NN - 1;   // clamp: dup rows, outputs guarded
  int ga1 = tm * 128 + rA0 + 64;   if (ga1 >= NN) ga1 = NN - 1;
  const float* a0p = F + (size_t)ga0 * F0 + qA0;
  const float* a1p = F + (size_t)ga1 * F0 + qA0;
  // only row NN-1's (kt=44,qA0=24) chunk reads past the features end -> patch (avoid NaN*0)
  const bool fix0 = (ga0 == NN - 1) && (qA0 == 24);
  const bool fix1 = (ga1 == NN - 1) && (qA0 == 24);

  const u16* Bb = BT + (size_t)tn * 128 * KP;
  u16* Bs0 = Bs + (wave * 64) * 8;           // wave-uniform LDS bases
  u16* Bs1 = Bs + (wave * 64 + 256) * 8;
  const size_t offB0 = (size_t)rA0 * KP + qA0;
  const size_t offB1 = (size_t)(rA0 + 64) * KP + qA0;
  uint4* As0w = (uint4*)As + c0;             // ds_write_b128 dest, 16B aligned
  uint4* As1w = (uint4*)As + (c0 + 256);

  // prologue: A loads for kt=0
  f32x4u va0 = *(const f32x4u*)(a0p);
  f32x4u vb0 = *(const f32x4u*)(a0p + 4);
  f32x4u va1 = *(const f32x4u*)(a1p);
  f32x4u vb1 = *(const f32x4u*)(a1p + 4);

  for (int kt = 0; kt < KP / 32; ++kt) {
    const int k0 = kt * 32;
    __syncthreads();
    uint4 w0, w1;
    w0.x = cvtpk(va0[0], va0[1]); w0.y = cvtpk(va0[2], va0[3]);
    w0.z = cvtpk(vb0[0], vb0[1]); w0.w = cvtpk(vb0[2], vb0[3]);
    w1.x = cvtpk(va1[0], va1[1]); w1.y = cvtpk(va1[2], va1[3]);
    w1.z = cvtpk(vb1[0], vb1[1]); w1.w = cvtpk(vb1[2], vb1[3]);
    *As0w = w0;
    *As1w = w1;
    gl16(Bb + offB0 + k0, Bs0);
    gl16(Bb + offB1 + k0, Bs1);
    __syncthreads();
    if (kt < 44) {   // prefetch next K-step; latency hides under MFMA phase
      const int kn = k0 + 32;
      va0 = *(const f32x4u*)(a0p + kn); vb0 = *(const f32x4u*)(a0p + kn + 4);
      va1 = *(const f32x4u*)(a1p + kn); vb1 = *(const f32x4u*)(a1p + kn + 4);
      if (kt == 43) {
        if (fix0) {
          float lastv = F[(size_t)(NN - 1) * F0 + 1432];
          va0[0] = lastv; va0[1] = 0.f; va0[2] = 0.f; va0[3] = 0.f;
          vb0[0] = 0.f;   vb0[1] = 0.f; vb0[2] = 0.f; vb0[3] = 0.f;
        }
        if (fix1) {
          float lastv = F[(size_t)(NN - 1) * F0 + 1432];
          va1[0] = lastv; va1[1] = 0.f; va1[2] = 0.f; va1[3] = 0.f;
          vb1[0] = 0.f;   vb1[1] = 0.f; vb1[2] = 0.f; vb1[3] = 0.f;
        }
      }
    }
    bf16x8 af[4], bfr[4];
#pragma unroll
    for (int mi = 0; mi < 4; ++mi)
      af[mi] = *(const bf16x8*)(As + ((waveM * 64 + mi * 16 + l16) * 32 + quad * 8));
#pragma unroll
    for (int ni = 0; ni < 4; ++ni)
      bfr[ni] = *(const bf16x8*)(Bs + ((waveN * 64 + ni * 16 + l16) * 32 + quad * 8));
#pragma unroll
    for (int mi = 0; mi < 4; ++mi)
#pragma unroll
      for (int ni = 0; ni < 4; ++ni)
        acc[mi][ni] = __builtin_amdgcn_mfma_f32_16x16x32_bf16(af[mi], bfr[ni], acc[mi][ni], 0, 0, 0);
  }

  // C/D: col = lane&15, row = quad*4 + reg  (verified m89/m91)
  const int rbase = tm * 128 + waveM * 64 + quad * 4;
  const int cbase = tn * 128 + waveN * 64 + l16;
#pragma unroll
  for (int mi = 0; mi < 4; ++mi) {
#pragma unroll
    for (int e = 0; e < 4; ++e) {
      const int i = rbase + mi * 16 + e;
      if (i < NN) {
        const float cs = csrc[i];
#pragma unroll
        for (int ni = 0; ni < 4; ++ni)
          H[(size_t)i * D1 + cbase + ni * 16] = f2bf(acc[mi][ni][e] * cs);
      }
    }
  }
}

// ---------------- fused SpMM1+post1: x1s[d] = relu(sum_{s in N(d)} h1[s] * cdst[d] + b1) * csrc[d] ----------------
__global__ __launch_bounds__(256) void k_spmm1f(const int* __restrict__ row, const int* __restrict__ csr,
                                                const u16* __restrict__ h1, const float* __restrict__ cdst,
                                                const float* __restrict__ csrc, const float* __restrict__ b1,
                                                u16* __restrict__ x) {
  const int d = blockIdx.x * 4 + (threadIdx.x >> 6);   // grid exact: 12500*4 = NN
  const int lane = threadIdx.x & 63;
  const int rs = row[d], re = row[d + 1];
  float a0 = 0.f, a1 = 0.f, a2 = 0.f, a3 = 0.f;
  int e = rs;
  for (; e + 3 < re; e += 4) {
    const int s0 = csr[e], s1 = csr[e + 1], s2 = csr[e + 2], s3 = csr[e + 3];
    const ushort4 v0 = *(const ushort4*)(h1 + (size_t)s0 * D1 + lane * 4);
    const ushort4 v1 = *(const ushort4*)(h1 + (size_t)s1 * D1 + lane * 4);
    const ushort4 v2 = *(const ushort4*)(h1 + (size_t)s2 * D1 + lane * 4);
    const ushort4 v3 = *(const ushort4*)(h1 + (size_t)s3 * D1 + lane * 4);
    a0 += (bf2f(v0.x) + bf2f(v1.x)) + (bf2f(v2.x) + bf2f(v3.x));
    a1 += (bf2f(v0.y) + bf2f(v1.y)) + (bf2f(v2.y) + bf2f(v3.y));
    a2 += (bf2f(v0.z) + bf2f(v1.z)) + (bf2f(v2.z) + bf2f(v3.z));
    a3 += (bf2f(v0.w) + bf2f(v1.w)) + (bf2f(v2.w) + bf2f(v3.w));
  }
  for (; e < re; ++e) {
    const int s0 = csr[e];
    const ushort4 v0 = *(const ushort4*)(h1 + (size_t)s0 * D1 + lane * 4);
    a0 += bf2f(v0.x); a1 += bf2f(v0.y); a2 += bf2f(v0.z); a3 += bf2f(v0.w);
  }
  const float cd = cdst[d], cs = csrc[d];
  const float4 bb = *(const float4*)(b1 + lane * 4);
  const float r0 = fmaxf(a0 * cd + bb.x, 0.f) * cs;
  const float r1 = fmaxf(a1 * cd + bb.y, 0.f) * cs;
  const float r2 = fmaxf(a2 * cd + bb.z, 0.f) * cs;
  const float r3 = fmaxf(a3 * cd + bb.w, 0.f) * cs;
  ushort4 o;
  o.x = f2bf(r0); o.y = f2bf(r1); o.z = f2bf(r2); o.w = f2bf(r3);
  *(ushort4*)(x + (size_t)d * D1 + lane * 4) = o;
}

// ---------------- GEMM2: x1s[*][256] @ W2T[32][256]^T -> h2 bf16 [NN][32] ----------------
__global__ __launch_bounds__(256) void k_gemm2(const u16* __restrict__ A, const u16* __restrict__ BT,
                                               u16* __restrict__ H) {
  __shared__ u16 As[128 * 32];
  __shared__ u16 Bs[32 * 32];
  const int tid = threadIdx.x;
  const int wave = tid >> 6, lane = tid & 63;
  const int l16 = lane & 15, quad = lane >> 4;
  const int tm = blockIdx.x;

  f32x4 acc[2][2];
#pragma unroll
  for (int mi = 0; mi < 2; ++mi)
#pragma unroll
    for (int ni = 0; ni < 2; ++ni) acc[mi][ni] = f32x4{0.f, 0.f, 0.f, 0.f};

  const int r0 = tid >> 2, q0 = (tid & 3) * 8;
  int rowA0 = tm * 128 + r0;      if (rowA0 >= NN) rowA0 = NN - 1;
  int rowA1 = tm * 128 + r0 + 64; if (rowA1 >= NN) rowA1 = NN - 1;
  for (int kt = 0; kt < 8; ++kt) {
    const int k0 = kt * 32;
    __syncthreads();
    uint4 v0 = *(const uint4*)(A + (size_t)rowA0 * D1 + k0 + q0);
    uint4 v1 = *(const uint4*)(A + (size_t)rowA1 * D1 + k0 + q0);
    *(uint4*)(As + r0 * 32 + q0) = v0;
    *(uint4*)(As + (r0 + 64) * 32 + q0) = v1;
    if (tid < 128) {
      uint4 vb = *(const uint4*)(BT + (size_t)r0 * D1 + k0 + q0);
      *(uint4*)(Bs + r0 * 32 + q0) = vb;
    }
    __syncthreads();
    bf16x8 af[2], bfr[2];
#pragma unroll
    for (int mi = 0; mi < 2; ++mi)
      af[mi] = *(const bf16x8*)(As + ((wave * 32 + mi * 16 + l16) * 32 + quad * 8));
#pragma unroll
    for (int ni = 0; ni < 2; ++ni)
      bfr[ni] = *(const bf16x8*)(Bs + ((ni * 16 + l16) * 32 + quad * 8));
#pragma unroll
    for (int mi = 0; mi < 2; ++mi)
#pragma unroll
      for (int ni = 0; ni < 2; ++ni)
        acc[mi][ni] = __builtin_amdgcn_mfma_f32_16x16x32_bf16(af[mi], bfr[ni], acc[mi][ni], 0, 0, 0);
  }

  const int rbase = tm * 128 + wave * 32 + quad * 4;
#pragma unroll
  for (int mi = 0; mi < 2; ++mi)
#pragma unroll
    for (int e = 0; e < 4; ++e) {
      const int i = rbase + mi * 16 + e;
      if (i < NN) {
#pragma unroll
        for (int ni = 0; ni < 2; ++ni)
          H[(size_t)i * D2 + ni * 16 + l16] = f2bf(acc[mi][ni][e]);
      }
    }
}

// ---------------- fused SpMM2+post2 ----------------
__global__ __launch_bounds__(256) void k_spmm2f(const int* __restrict__ row, const int* __restrict__ csr,
                                                const u16* __restrict__ h2, const float* __restrict__ cdst,
                                                const float* __restrict__ csrc, const float* __restrict__ b2,
                                                u16* __restrict__ x) {
  const int t = threadIdx.x;
  const int d = blockIdx.x * 8 + (t >> 5);  // grid exact: 6250*8 = NN
  const int f = t & 31;
  const int rs = row[d], re = row[d + 1];
  float acc = 0.f;
  int e = rs;
  for (; e + 3 < re; e += 4) {
    const int s0 = csr[e], s1 = csr[e + 1], s2 = csr[e + 2], s3 = csr[e + 3];
    acc += (bf2f(h2[(size_t)s0 * D2 + f]) + bf2f(h2[(size_t)s1 * D2 + f])) +
           (bf2f(h2[(size_t)s2 * D2 + f]) + bf2f(h2[(size_t)s3 * D2 + f]));
  }
  for (; e < re; ++e) acc += bf2f(h2[(size_t)csr[e] * D2 + f]);
  const float v = acc * cdst[d] + b2[f];
  x[(size_t)d * D2 + f] = f2bf(fmaxf(v, 0.f) * csrc[d]);
}

// ---------------- layer3 matmul: h3[i][c] = sum_k x2s[i][k]*W3[k][c], f32 [NN][8] ----------------
__global__ __launch_bounds__(256) void k_l3(const u16* __restrict__ x, const float* __restrict__ W3,
                                            float* __restrict__ h3) {
  __shared__ float w3s[224];
  const int t = threadIdx.x;
  if (t < 224) w3s[t] = W3[t];
  __syncthreads();
  const int i = blockIdx.x * 256 + t;
  if (i >= NN) return;
  const uint4* p = (const uint4*)(x + (size_t)i * D2);
  union { uint4 v[4]; u16 s[32]; } u;
  u.v[0] = p[0]; u.v[1] = p[1]; u.v[2] = p[2]; u.v[3] = p[3];
  float acc[7];
#pragma unroll
  for (int c = 0; c < 7; ++c) acc[c] = 0.f;
#pragma unroll
  for (int k = 0; k < 32; ++k) {
    const float xv = bf2f(u.s[k]);
#pragma unroll
    for (int c = 0; c < 7; ++c) acc[c] += xv * w3s[k * 7 + c];
  }
  float* o = h3 + (size_t)i * 8;
#pragma unroll
  for (int c = 0; c < 7; ++c) o[c] = acc[c];
}

// ---------------- fused SpMM3 + bias + log_softmax: 8 lanes per node ----------------
__global__ __launch_bounds__(256) void k_spmm3f(const int* __restrict__ row, const int* __restrict__ csr,
                                                const float* __restrict__ h3, const float* __restrict__ cdst,
                                                const float* __restrict__ b3, float* __restrict__ out) {
  const int t = threadIdx.x;
  const int d = blockIdx.x * 32 + (t >> 3);
  const int c = t & 7;
  if (d >= NN) return;
  const int rs = row[d], re = row[d + 1];
  float acc = 0.f;
  if (c < 7) {
    int e = rs;
    for (; e + 1 < re; e += 2)
      acc += h3[(size_t)csr[e] * 8 + c] + h3[(size_t)csr[e + 1] * 8 + c];
    if (e < re) acc += h3[(size_t)csr[e] * 8 + c];
  }
  const float v = (c < 7) ? (acc * cdst[d] + b3[c]) : -INFINITY;
  float m = v;
  m = fmaxf(m, __shfl_xor(m, 1));
  m = fmaxf(m, __shfl_xor(m, 2));
  m = fmaxf(m, __shfl_xor(m, 4));
  float s = (c < 7) ? expf(v - m) : 0.f;
  s += __shfl_xor(s, 1);
  s += __shfl_xor(s, 2);
  s += __shfl_xor(s, 4);
  const float l = logf(s);
  if (c < 7) out[(size_t)d * 7 + c] = v - m - l;
}

// ---------------- workspace layout (bytes) ----------------
static const size_t O_CSRC = 0;           // f32 [NN]
static const size_t O_CDST = 200192;      // f32 [NN]
static const size_t O_ROW  = 400384;      // int [NN+1]
static const size_t O_CUR  = 601088;      // int [NN]
static const size_t O_CNTS = 801792;      // int [NN]
static const size_t O_CNTD = 1002496;     // int [NN]
static const size_t O_BSUM = 1203200;     // int [256]
static const size_t O_BOFF = 1204224;     // int [256]
static const size_t O_CSR  = 1205248;     // int [NE]
static const size_t O_W1T  = 4405248;     // bf16 [256][KP]
static const size_t O_W2T  = 5142528;     // bf16 [32][256]
static const size_t O_H1   = 5158912;     // bf16 [NN][256]
static const size_t O_X1S  = 30758912;    // bf16 [NN][256]
static const size_t O_H2   = O_X1S + 25600000;     // bf16 [NN][32]
static const size_t O_X2S  = O_X1S + 28800000;     // bf16 [NN][32]
static const size_t O_H3   = O_X1S + 32000000;     // f32 [NN][8]

extern "C" void kernel_launch(void* const* d_in, const int* in_sizes, int n_in,
                              void* d_out, int out_size, void* d_ws, size_t ws_size,
                              hipStream_t stream) {
  const float* feat = (const float*)d_in[0];
  const int* ei     = (const int*)d_in[1];
  const float* W1   = (const float*)d_in[2];
  const float* b1   = (const float*)d_in[3];
  const float* W2   = (const float*)d_in[4];
  const float* b2   = (const float*)d_in[5];
  const float* W3   = (const float*)d_in[6];
  const float* b3   = (const float*)d_in[7];
  float* out = (float*)d_out;

  char* ws = (char*)d_ws;
  float* c_src = (float*)(ws + O_CSRC);
  float* c_dst = (float*)(ws + O_CDST);
  int* row  = (int*)(ws + O_ROW);
  int* cur  = (int*)(ws + O_CUR);
  int* cnts = (int*)(ws + O_CNTS);
  int* cntd = (int*)(ws + O_CNTD);
  int* bsum = (int*)(ws + O_BSUM);
  int* boff = (int*)(ws + O_BOFF);
  int* csr  = (int*)(ws + O_CSR);
  u16* W1T  = (u16*)(ws + O_W1T);
  u16* W2T  = (u16*)(ws + O_W2T);
  u16* h1   = (u16*)(ws + O_H1);
  u16* x1s  = (u16*)(ws + O_X1S);
  u16* h2   = (u16*)(ws + O_H2);
  u16* x2s  = (u16*)(ws + O_X2S);
  float* h3 = (float*)(ws + O_H3);

  // CSR build + norms
  hipMemsetAsync(cnts, 0, (size_t)NN * 4, stream);
  hipMemsetAsync(cntd, 0, (size_t)NN * 4, stream);
  k_hist<<<HB, 256, 0, stream>>>(ei, cnts, cntd);
  k_scan1<<<NB, 256, 0, stream>>>(cntd, bsum);
  k_scan2<<<1, 256, 0, stream>>>(bsum, boff);
  k_scan3<<<NB, 256, 0, stream>>>(cntd, cnts, boff, row, cur, c_dst, c_src);
  // scatter runs concurrently with weight prep (one dispatch)
  k_scatprep<<<SB + KP + 32, 256, 0, stream>>>(ei, cur, csr, W1, W2, W1T, W2T);

  // layer 1 (A converted f32->bf16 inside gemm1 staging)
  k_gemm1<<<782, 256, 0, stream>>>(feat, W1T, c_src, h1);
  k_spmm1f<<<NN / 4, 256, 0, stream>>>(row, csr, h1, c_dst, c_src, b1, x1s);

  // layer 2
  k_gemm2<<<MP / 128, 256, 0, stream>>>(x1s, W2T, h2);
  k_spmm2f<<<NN / 8, 256, 0, stream>>>(row, csr, h2, c_dst, c_src, b2, x2s);

  // layer 3 + log_softmax
  k_l3<<<(NN + 255) / 256, 256, 0, stream>>>(x2s, W3, h3);
  k_spmm3f<<<(NN + 31) / 32, 256, 0, stream>>>(row, csr, h3, c_dst, b3, out);
}

// Round 6
// 693.106 us; speedup vs baseline: 1.0863x; 1.0248x over previous
//
#include <hip/hip_runtime.h>
#include <math.h>

typedef unsigned short u16;
typedef unsigned int u32;
typedef __attribute__((ext_vector_type(8))) short bf16x8;   // 8 bf16 (4 VGPRs)
typedef __attribute__((ext_vector_type(4))) float f32x4;    // 4 fp32 acc
typedef float f32x4u __attribute__((vector_size(16), aligned(4)));  // unaligned-capable float4

#define NN 50000    // nodes
#define NE 800000   // edges
#define F0 1433     // in feats
#define KP2 1472    // padded K for gemm1 (23 * 64)
#define KT1 23      // gemm1 K-steps
#define MP 50048    // padded M (391 * 128)
#define D1 256
#define D2 32
#define NB 196      // scan blocks: 196*256 = 50176 >= NN
#define HB 3125     // hist blocks: 3125*256 >= NE
#define SB 3125     // scatter blocks

__device__ __forceinline__ float bf2f(u16 h) { return __uint_as_float(((u32)h) << 16); }
__device__ __forceinline__ u16 f2bf(float f) {
  u32 u = __float_as_uint(f);
  u32 r = (u + 0x7FFFu + ((u >> 16) & 1u)) >> 16;  // RNE
  return (u16)r;
}
// packed f32 pair -> bf16 pair (RNE), single HW instr
__device__ __forceinline__ u32 cvtpk(float lo, float hi) {
  u32 r;
  asm("v_cvt_pk_bf16_f32 %0, %1, %2" : "=v"(r) : "v"(lo), "v"(hi));
  return r;
}

// async global->LDS, 16B per lane; LDS dest is wave-uniform base + lane*16
__device__ __forceinline__ void gl16(const void* g, void* l) {
  __builtin_amdgcn_global_load_lds((const __attribute__((address_space(1))) u32*)g,
                                   (__attribute__((address_space(3))) u32*)l, 16, 0, 0);
}

// ---------------- edge histogram ----------------
__global__ __launch_bounds__(256) void k_hist(const int* __restrict__ ei,
                                              int* __restrict__ cs, int* __restrict__ cd) {
  const int e = blockIdx.x * 256 + threadIdx.x;
  if (e < NE) {
    atomicAdd(&cs[ei[e]], 1);
    atomicAdd(&cd[ei[NE + e]], 1);
  }
}

__global__ __launch_bounds__(256) void k_scan1(const int* __restrict__ cd, int* __restrict__ bsum) {
  __shared__ int sh[256];
  const int t = threadIdx.x;
  const int i = blockIdx.x * 256 + t;
  sh[t] = (i < NN) ? cd[i] : 0;
  __syncthreads();
  for (int o = 128; o > 0; o >>= 1) {
    if (t < o) sh[t] += sh[t + o];
    __syncthreads();
  }
  if (t == 0) bsum[blockIdx.x] = sh[0];
}

__global__ __launch_bounds__(256) void k_scan2(const int* __restrict__ bsum, int* __restrict__ boff) {
  __shared__ int sh[256];
  const int t = threadIdx.x;
  const int v = (t < NB) ? bsum[t] : 0;
  sh[t] = v;
  __syncthreads();
  for (int o = 1; o < 256; o <<= 1) {
    int x = (t >= o) ? sh[t - o] : 0;
    __syncthreads();
    sh[t] += x;
    __syncthreads();
  }
  if (t < NB) boff[t] = sh[t] - v;  // exclusive
}

// exclusive scan per block + base; emits row_start, cursor, and both norms
__global__ __launch_bounds__(256) void k_scan3(const int* __restrict__ cd, const int* __restrict__ cs,
                                               const int* __restrict__ boff,
                                               int* __restrict__ row, int* __restrict__ cur,
                                               float* __restrict__ cdst, float* __restrict__ csrc) {
  __shared__ int sh[256];
  const int t = threadIdx.x;
  const int i = blockIdx.x * 256 + t;
  const int v = (i < NN) ? cd[i] : 0;
  sh[t] = v;
  __syncthreads();
  for (int o = 1; o < 256; o <<= 1) {
    int x = (t >= o) ? sh[t - o] : 0;
    __syncthreads();
    sh[t] += x;
    __syncthreads();
  }
  if (i < NN) {
    const int start = boff[blockIdx.x] + sh[t] - v;
    row[i] = start;
    cur[i] = start;
    if (i == NN - 1) row[NN] = start + v;
    cdst[i] = rsqrtf(fmaxf((float)v, 1.0f));
    csrc[i] = rsqrtf(fmaxf((float)cs[i], 1.0f));
  }
}

// ---------------- merged: CSR scatter (blocks 0..SB) + weight prep (blocks SB..) ----------------
// W1 fp32[F0][256] -> bf16 W1T[256][KP2] (zero pad cols); W2 -> W2T[32][256]
__global__ __launch_bounds__(256) void k_scatprep(const int* __restrict__ ei,
                                                  int* __restrict__ cur, int* __restrict__ csr,
                                                  const float* __restrict__ W1, const float* __restrict__ W2,
                                                  u16* __restrict__ W1T, u16* __restrict__ W2T) {
  const int bid = blockIdx.x;
  const int t = threadIdx.x;
  if (bid < SB) {
    const int e = bid * 256 + t;
    if (e < NE) {
      const int d = ei[NE + e];
      const int p = atomicAdd(&cur[d], 1);
      csr[p] = ei[e];
    }
    return;
  }
  const int b = bid - SB;
  if (b < KP2) {
    W1T[(size_t)t * KP2 + b] = (b < F0) ? f2bf(W1[(size_t)b * D1 + t]) : (u16)0;
  } else {
    const int idx = (b - KP2) * 256 + t;  // 0..8191
    const int k = idx & 255, n = idx >> 8;
    W2T[n * 256 + k] = f2bf(W2[k * 32 + n]);
  }
}

// ---------------- GEMM1: F f32[NN][1433] (staged-cvt bf16) @ W1T[256][KP2]^T -> h1 bf16 [NN][256], * c_src ----------------
// BK=64, 23 K-steps. LDS [128][64] u16 with 16B-chunk XOR swizzle: chunk(r,koc) at index r*8 + (koc^(r&7)).
// A: reg-staged (8 f32 loads -> cvt_pk -> swizzled ds_write_b128), prefetched one K-step ahead.
// B: gl16 with pre-swizzled GLOBAL source (linear LDS dest), swizzled ds_read.
__global__ __launch_bounds__(256) void k_gemm1(const float* __restrict__ F,
                                               const u16* __restrict__ BT,
                                               const float* __restrict__ csrc, u16* __restrict__ H) {
  __shared__ u16 As[128 * 64];
  __shared__ u16 Bs[128 * 64];
  const int tid = threadIdx.x;
  const int wave = tid >> 6, lane = tid & 63;
  const int l16 = lane & 15, quad = lane >> 4;
  const int waveM = wave & 1, waveN = wave >> 1;

  // nwg = 782 = 8*97 + 6: bijective XCD-chunked swizzle; tn-pair sharing an A-panel lands on one XCD's L2.
  const int wg = blockIdx.x;
  const int xcd = wg & 7, idx = wg >> 3;
  const int swz = (xcd < 6) ? xcd * 98 + idx : 588 + (xcd - 6) * 97 + idx;
  const int tn = swz & 1, tm = swz >> 1;

  f32x4 acc[4][4];
#pragma unroll
  for (int mi = 0; mi < 4; ++mi)
#pragma unroll
    for (int ni = 0; ni < 4; ++ni) acc[mi][ni] = f32x4{0.f, 0.f, 0.f, 0.f};

  // staging: 1024 16B chunks per tile; thread t owns chunks c_j = t + 256j (j=0..3)
  // chunk c: row r = c>>3 (r_j = (t>>3)+32j), k-chunk koc = c&7 (= t&7, same all j)
  const int ko = (tid & 7) * 8;          // k-offset within BK
  const int rx = (tid >> 3) & 7;         // r&7, same for all j (32j = 0 mod 8)
  const int wlow = (tid & 7) ^ rx;       // swizzled low-3 chunk bits

  int lastm = 0;                          // bitmask: chunk j reads true last row
  const float* ap[4];
#pragma unroll
  for (int j = 0; j < 4; ++j) {
    const int r = (tid >> 3) + 32 * j;
    int g = tm * 128 + r;
    if (g == NN - 1) lastm |= (1 << j);
    if (g >= NN) g = 0;                   // discarded rows: read row 0 (valid data, outputs guarded)
    ap[j] = F + (size_t)g * F0 + ko;
  }

  const u16* Bb = BT + (size_t)(tn * 128) * KP2;
  size_t bofs[4];
#pragma unroll
  for (int j = 0; j < 4; ++j)
    bofs[j] = (size_t)((tid >> 3) + 32 * j) * KP2 + wlow * 8;  // pre-swizzled global source

  uint4* Asw = (uint4*)As;

  // prologue: A loads for kt=0 (K0 = ko <= 56, always in-bounds)
  f32x4u va[4], vb[4];
#pragma unroll
  for (int j = 0; j < 4; ++j) {
    va[j] = *(const f32x4u*)(ap[j]);
    vb[j] = *(const f32x4u*)(ap[j] + 4);
  }

  for (int kt = 0; kt < KT1; ++kt) {
    const int k0 = kt * 64;
    __syncthreads();
    // stage A (swizzled ds_write_b128)
#pragma unroll
    for (int j = 0; j < 4; ++j) {
      uint4 w;
      w.x = cvtpk(va[j][0], va[j][1]); w.y = cvtpk(va[j][2], va[j][3]);
      w.z = cvtpk(vb[j][0], vb[j][1]); w.w = cvtpk(vb[j][2], vb[j][3]);
      Asw[((tid + 256 * j) & ~7) | wlow] = w;
    }
    // stage B (gl16, linear dest chunk c = wave*64 + lane + 256j)
#pragma unroll
    for (int j = 0; j < 4; ++j)
      gl16(Bb + bofs[j] + k0, (uint4*)Bs + (wave * 64 + 256 * j));
    __syncthreads();
    // prefetch A for kt+1 (full MFMA phase to cover latency)
    if (kt < KT1 - 1) {
      const int kn = k0 + 64;
      const bool tail = (kn == (KT1 - 1) * 64);   // next K-step is the last (k 1408..1471)
#pragma unroll
      for (int j = 0; j < 4; ++j) {
        if (tail && ((lastm >> j) & 1) && ko >= 24) {
          // row 49999: K0 = 1408+ko >= 1432 -> patch (avoid OOB read past features end)
          f32x4u z = {0.f, 0.f, 0.f, 0.f};
          f32x4u t0 = z;
          if (ko == 24) t0[0] = F[(size_t)NN * F0 - 1];  // k=1432 valid element
          va[j] = t0;
          vb[j] = z;
        } else {
          va[j] = *(const f32x4u*)(ap[j] + kn);
          vb[j] = *(const f32x4u*)(ap[j] + kn + 4);
        }
      }
    }
    // MFMA: 2 k-slices x 16
#pragma unroll
    for (int ks = 0; ks < 2; ++ks) {
      const int cq = ks * 4 + quad;
      bf16x8 af[4], bfr[4];
#pragma unroll
      for (int mi = 0; mi < 4; ++mi) {
        const int r = waveM * 64 + mi * 16 + l16;
        af[mi] = *(const bf16x8*)(As + r * 64 + ((cq ^ (r & 7)) << 3));
      }
#pragma unroll
      for (int ni = 0; ni < 4; ++ni) {
        const int r = waveN * 64 + ni * 16 + l16;
        bfr[ni] = *(const bf16x8*)(Bs + r * 64 + ((cq ^ (r & 7)) << 3));
      }
#pragma unroll
      for (int mi = 0; mi < 4; ++mi)
#pragma unroll
        for (int ni = 0; ni < 4; ++ni)
          acc[mi][ni] = __builtin_amdgcn_mfma_f32_16x16x32_bf16(af[mi], bfr[ni], acc[mi][ni], 0, 0, 0);
    }
  }

  // C/D: col = lane&15, row = quad*4 + reg  (verified m89/m91)
  const int rbase = tm * 128 + waveM * 64 + quad * 4;
  const int cbase = tn * 128 + waveN * 64 + l16;
#pragma unroll
  for (int mi = 0; mi < 4; ++mi) {
#pragma unroll
    for (int e = 0; e < 4; ++e) {
      const int i = rbase + mi * 16 + e;
      if (i < NN) {
        const float cs = csrc[i];
#pragma unroll
        for (int ni = 0; ni < 4; ++ni)
          H[(size_t)i * D1 + cbase + ni * 16] = f2bf(acc[mi][ni][e] * cs);
      }
    }
  }
}

// ---------------- fused SpMM1+post1: x1s[d] = relu(sum_{s in N(d)} h1[s] * cdst[d] + b1) * csrc[d] ----------------
__global__ __launch_bounds__(256) void k_spmm1f(const int* __restrict__ row, const int* __restrict__ csr,
                                                const u16* __restrict__ h1, const float* __restrict__ cdst,
                                                const float* __restrict__ csrc, const float* __restrict__ b1,
                                                u16* __restrict__ x) {
  const int d = blockIdx.x * 4 + (threadIdx.x >> 6);   // grid exact: 12500*4 = NN
  const int lane = threadIdx.x & 63;
  const int rs = row[d], re = row[d + 1];
  float a0 = 0.f, a1 = 0.f, a2 = 0.f, a3 = 0.f;
  int e = rs;
  for (; e + 3 < re; e += 4) {
    const int s0 = csr[e], s1 = csr[e + 1], s2 = csr[e + 2], s3 = csr[e + 3];
    const ushort4 v0 = *(const ushort4*)(h1 + (size_t)s0 * D1 + lane * 4);
    const ushort4 v1 = *(const ushort4*)(h1 + (size_t)s1 * D1 + lane * 4);
    const ushort4 v2 = *(const ushort4*)(h1 + (size_t)s2 * D1 + lane * 4);
    const ushort4 v3 = *(const ushort4*)(h1 + (size_t)s3 * D1 + lane * 4);
    a0 += (bf2f(v0.x) + bf2f(v1.x)) + (bf2f(v2.x) + bf2f(v3.x));
    a1 += (bf2f(v0.y) + bf2f(v1.y)) + (bf2f(v2.y) + bf2f(v3.y));
    a2 += (bf2f(v0.z) + bf2f(v1.z)) + (bf2f(v2.z) + bf2f(v3.z));
    a3 += (bf2f(v0.w) + bf2f(v1.w)) + (bf2f(v2.w) + bf2f(v3.w));
  }
  for (; e < re; ++e) {
    const int s0 = csr[e];
    const ushort4 v0 = *(const ushort4*)(h1 + (size_t)s0 * D1 + lane * 4);
    a0 += bf2f(v0.x); a1 += bf2f(v0.y); a2 += bf2f(v0.z); a3 += bf2f(v0.w);
  }
  const float cd = cdst[d], cs = csrc[d];
  const float4 bb = *(const float4*)(b1 + lane * 4);
  const float r0 = fmaxf(a0 * cd + bb.x, 0.f) * cs;
  const float r1 = fmaxf(a1 * cd + bb.y, 0.f) * cs;
  const float r2 = fmaxf(a2 * cd + bb.z, 0.f) * cs;
  const float r3 = fmaxf(a3 * cd + bb.w, 0.f) * cs;
  ushort4 o;
  o.x = f2bf(r0); o.y = f2bf(r1); o.z = f2bf(r2); o.w = f2bf(r3);
  *(ushort4*)(x + (size_t)d * D1 + lane * 4) = o;
}

// ---------------- GEMM2: x1s[*][256] @ W2T[32][256]^T -> h2 bf16 [NN][32] ----------------
__global__ __launch_bounds__(256) void k_gemm2(const u16* __restrict__ A, const u16* __restrict__ BT,
                                               u16* __restrict__ H) {
  __shared__ u16 As[128 * 32];
  __shared__ u16 Bs[32 * 32];
  const int tid = threadIdx.x;
  const int wave = tid >> 6, lane = tid & 63;
  const int l16 = lane & 15, quad = lane >> 4;
  const int tm = blockIdx.x;

  f32x4 acc[2][2];
#pragma unroll
  for (int mi = 0; mi < 2; ++mi)
#pragma unroll
    for (int ni = 0; ni < 2; ++ni) acc[mi][ni] = f32x4{0.f, 0.f, 0.f, 0.f};

  const int r0 = tid >> 2, q0 = (tid & 3) * 8;
  int rowA0 = tm * 128 + r0;      if (rowA0 >= NN) rowA0 = NN - 1;
  int rowA1 = tm * 128 + r0 + 64; if (rowA1 >= NN) rowA1 = NN - 1;
  for (int kt = 0; kt < 8; ++kt) {
    const int k0 = kt * 32;
    __syncthreads();
    uint4 v0 = *(const uint4*)(A + (size_t)rowA0 * D1 + k0 + q0);
    uint4 v1 = *(const uint4*)(A + (size_t)rowA1 * D1 + k0 + q0);
    *(uint4*)(As + r0 * 32 + q0) = v0;
    *(uint4*)(As + (r0 + 64) * 32 + q0) = v1;
    if (tid < 128) {
      uint4 vb = *(const uint4*)(BT + (size_t)r0 * D1 + k0 + q0);
      *(uint4*)(Bs + r0 * 32 + q0) = vb;
    }
    __syncthreads();
    bf16x8 af[2], bfr[2];
#pragma unroll
    for (int mi = 0; mi < 2; ++mi)
      af[mi] = *(const bf16x8*)(As + ((wave * 32 + mi * 16 + l16) * 32 + quad * 8));
#pragma unroll
    for (int ni = 0; ni < 2; ++ni)
      bfr[ni] = *(const bf16x8*)(Bs + ((ni * 16 + l16) * 32 + quad * 8));
#pragma unroll
    for (int mi = 0; mi < 2; ++mi)
#pragma unroll
      for (int ni = 0; ni < 2; ++ni)
        acc[mi][ni] = __builtin_amdgcn_mfma_f32_16x16x32_bf16(af[mi], bfr[ni], acc[mi][ni], 0, 0, 0);
  }

  const int rbase = tm * 128 + wave * 32 + quad * 4;
#pragma unroll
  for (int mi = 0; mi < 2; ++mi)
#pragma unroll
    for (int e = 0; e < 4; ++e) {
      const int i = rbase + mi * 16 + e;
      if (i < NN) {
#pragma unroll
        for (int ni = 0; ni < 2; ++ni)
          H[(size_t)i * D2 + ni * 16 + l16] = f2bf(acc[mi][ni][e]);
      }
    }
}

// ---------------- fused SpMM2+post2 ----------------
__global__ __launch_bounds__(256) void k_spmm2f(const int* __restrict__ row, const int* __restrict__ csr,
                                                const u16* __restrict__ h2, const float* __restrict__ cdst,
                                                const float* __restrict__ csrc, const float* __restrict__ b2,
                                                u16* __restrict__ x) {
  const int t = threadIdx.x;
  const int d = blockIdx.x * 8 + (t >> 5);  // grid exact: 6250*8 = NN
  const int f = t & 31;
  const int rs = row[d], re = row[d + 1];
  float acc = 0.f;
  int e = rs;
  for (; e + 3 < re; e += 4) {
    const int s0 = csr[e], s1 = csr[e + 1], s2 = csr[e + 2], s3 = csr[e + 3];
    acc += (bf2f(h2[(size_t)s0 * D2 + f]) + bf2f(h2[(size_t)s1 * D2 + f])) +
           (bf2f(h2[(size_t)s2 * D2 + f]) + bf2f(h2[(size_t)s3 * D2 + f]));
  }
  for (; e < re; ++e) acc += bf2f(h2[(size_t)csr[e] * D2 + f]);
  const float v = acc * cdst[d] + b2[f];
  x[(size_t)d * D2 + f] = f2bf(fmaxf(v, 0.f) * csrc[d]);
}

// ---------------- layer3 matmul: h3[i][c] = sum_k x2s[i][k]*W3[k][c], f32 [NN][8] ----------------
__global__ __launch_bounds__(256) void k_l3(const u16* __restrict__ x, const float* __restrict__ W3,
                                            float* __restrict__ h3) {
  __shared__ float w3s[224];
  const int t = threadIdx.x;
  if (t < 224) w3s[t] = W3[t];
  __syncthreads();
  const int i = blockIdx.x * 256 + t;
  if (i >= NN) return;
  const uint4* p = (const uint4*)(x + (size_t)i * D2);
  union { uint4 v[4]; u16 s[32]; } u;
  u.v[0] = p[0]; u.v[1] = p[1]; u.v[2] = p[2]; u.v[3] = p[3];
  float acc[7];
#pragma unroll
  for (int c = 0; c < 7; ++c) acc[c] = 0.f;
#pragma unroll
  for (int k = 0; k < 32; ++k) {
    const float xv = bf2f(u.s[k]);
#pragma unroll
    for (int c = 0; c < 7; ++c) acc[c] += xv * w3s[k * 7 + c];
  }
  float* o = h3 + (size_t)i * 8;
#pragma unroll
  for (int c = 0; c < 7; ++c) o[c] = acc[c];
}

// ---------------- fused SpMM3 + bias + log_softmax: 8 lanes per node ----------------
__global__ __launch_bounds__(256) void k_spmm3f(const int* __restrict__ row, const int* __restrict__ csr,
                                                const float* __restrict__ h3, const float* __restrict__ cdst,
                                                const float* __restrict__ b3, float* __restrict__ out) {
  const int t = threadIdx.x;
  const int d = blockIdx.x * 32 + (t >> 3);
  const int c = t & 7;
  if (d >= NN) return;
  const int rs = row[d], re = row[d + 1];
  float acc = 0.f;
  if (c < 7) {
    int e = rs;
    for (; e + 1 < re; e += 2)
      acc += h3[(size_t)csr[e] * 8 + c] + h3[(size_t)csr[e + 1] * 8 + c];
    if (e < re) acc += h3[(size_t)csr[e] * 8 + c];
  }
  const float v = (c < 7) ? (acc * cdst[d] + b3[c]) : -INFINITY;
  float m = v;
  m = fmaxf(m, __shfl_xor(m, 1));
  m = fmaxf(m, __shfl_xor(m, 2));
  m = fmaxf(m, __shfl_xor(m, 4));
  float s = (c < 7) ? expf(v - m) : 0.f;
  s += __shfl_xor(s, 1);
  s += __shfl_xor(s, 2);
  s += __shfl_xor(s, 4);
  const float l = logf(s);
  if (c < 7) out[(size_t)d * 7 + c] = v - m - l;
}

// ---------------- workspace layout (bytes) ----------------
static const size_t O_CSRC = 0;           // f32 [NN]
static const size_t O_CDST = 200192;      // f32 [NN]
static const size_t O_ROW  = 400384;      // int [NN+1]
static const size_t O_CUR  = 601088;      // int [NN]
static const size_t O_CNTS = 801792;      // int [NN]
static const size_t O_CNTD = 1002496;     // int [NN]
static const size_t O_BSUM = 1203200;     // int [256]
static const size_t O_BOFF = 1204224;     // int [256]
static const size_t O_CSR  = 1205248;     // int [NE]
static const size_t O_W1T  = 4405248;     // bf16 [256][KP2] = 753,664 B
static const size_t O_W2T  = 5158912;     // bf16 [32][256]
static const size_t O_H1   = 5175296;     // bf16 [NN][256]
static const size_t O_X1S  = 30775296;    // bf16 [NN][256]
static const size_t O_H2   = 56375296;    // bf16 [NN][32]
static const size_t O_X2S  = 59575296;    // bf16 [NN][32]
static const size_t O_H3   = 62775296;    // f32 [NN][8]

extern "C" void kernel_launch(void* const* d_in, const int* in_sizes, int n_in,
                              void* d_out, int out_size, void* d_ws, size_t ws_size,
                              hipStream_t stream) {
  const float* feat = (const float*)d_in[0];
  const int* ei     = (const int*)d_in[1];
  const float* W1   = (const float*)d_in[2];
  const float* b1   = (const float*)d_in[3];
  const float* W2   = (const float*)d_in[4];
  const float* b2   = (const float*)d_in[5];
  const float* W3   = (const float*)d_in[6];
  const float* b3   = (const float*)d_in[7];
  float* out = (float*)d_out;

  char* ws = (char*)d_ws;
  float* c_src = (float*)(ws + O_CSRC);
  float* c_dst = (float*)(ws + O_CDST);
  int* row  = (int*)(ws + O_ROW);
  int* cur  = (int*)(ws + O_CUR);
  int* cnts = (int*)(ws + O_CNTS);
  int* cntd = (int*)(ws + O_CNTD);
  int* bsum = (int*)(ws + O_BSUM);
  int* boff = (int*)(ws + O_BOFF);
  int* csr  = (int*)(ws + O_CSR);
  u16* W1T  = (u16*)(ws + O_W1T);
  u16* W2T  = (u16*)(ws + O_W2T);
  u16* h1   = (u16*)(ws + O_H1);
  u16* x1s  = (u16*)(ws + O_X1S);
  u16* h2   = (u16*)(ws + O_H2);
  u16* x2s  = (u16*)(ws + O_X2S);
  float* h3 = (float*)(ws + O_H3);

  // CSR build + norms
  hipMemsetAsync(cnts, 0, (size_t)NN * 4, stream);
  hipMemsetAsync(cntd, 0, (size_t)NN * 4, stream);
  k_hist<<<HB, 256, 0, stream>>>(ei, cnts, cntd);
  k_scan1<<<NB, 256, 0, stream>>>(cntd, bsum);
  k_scan2<<<1, 256, 0, stream>>>(bsum, boff);
  k_scan3<<<NB, 256, 0, stream>>>(cntd, cnts, boff, row, cur, c_dst, c_src);
  // scatter runs concurrently with weight prep (one dispatch)
  k_scatprep<<<SB + KP2 + 32, 256, 0, stream>>>(ei, cur, csr, W1, W2, W1T, W2T);

  // layer 1 (A converted f32->bf16 inside gemm1 staging; BK=64)
  k_gemm1<<<782, 256, 0, stream>>>(feat, W1T, c_src, h1);
  k_spmm1f<<<NN / 4, 256, 0, stream>>>(row, csr, h1, c_dst, c_src, b1, x1s);

  // layer 2
  k_gemm2<<<MP / 128, 256, 0, stream>>>(x1s, W2T, h2);
  k_spmm2f<<<NN / 8, 256, 0, stream>>>(row, csr, h2, c_dst, c_src, b2, x2s);

  // layer 3 + log_softmax
  k_l3<<<(NN + 255) / 256, 256, 0, stream>>>(x2s, W3, h3);
  k_spmm3f<<<(NN + 31) / 32, 256, 0, stream>>>(row, csr, h3, c_dst, b3, out);
}